// Round 1
// baseline (759.834 us; speedup 1.0000x reference)
//
#include <hip/hip_runtime.h>
#include <hip/hip_bf16.h>

// Problem constants (B, L, D, R) from the reference.
constexpr int Bb = 8, Ls = 2048, Dd = 512, Rr = 512;
constexpr int M1 = Bb * Ls;  // 16384 rows of the (B*L, ...) matrices

// ---------------------------------------------------------------------------
// inv_w2[i] = 1 / widths[i]^2   (elementwise, R*D)
// ---------------------------------------------------------------------------
__global__ __launch_bounds__(256) void inv_w2_kernel(const float* __restrict__ w,
                                                     float* __restrict__ iw, int n) {
  int i = blockIdx.x * 256 + threadIdx.x;
  if (i < n) {
    float x = w[i];
    iw[i] = 1.0f / (x * x);
  }
}

// ---------------------------------------------------------------------------
// Generic 64x64 tiled fp32 GEMM: C = A * B (+bias), optional B transposed.
//   A: M x K row-major (per batch, stride sAb)
//   B: BT ? (N x K) : (K x N) row-major (stride sBb)
//   C: M x N row-major (stride sCb)
//   BIAS: 0 = none, 1 = bias[n] (per column), 2 = bias[m] (per row)
// 256 threads, each computes 4x4. LDS tiles stored K-major ([BK][dim+4]),
// pad 4 keeps 16B alignment for float4 reads and stride 68 = 4 mod 32
// (2-way bank aliasing only, free on gfx950).
// ---------------------------------------------------------------------------
template <bool BT, int BIAS>
__global__ __launch_bounds__(256) void gemm_tile(
    const float* __restrict__ A, const float* __restrict__ B,
    const float* __restrict__ bias, float* __restrict__ C,
    int M, int N, int K, long sAb, long sBb, long sCb) {
  constexpr int BM = 64, BN = 64, BK = 16, PAD = 4;
  __shared__ float As[BK][BM + PAD];
  __shared__ float Bs[BK][BN + PAD];
  const long bz = blockIdx.z;
  const float* Ab = A + bz * sAb;
  const float* Bp = B + bz * sBb;
  float* Cb = C + bz * sCb;
  const int n0 = blockIdx.x * BN;
  const int m0 = blockIdx.y * BM;
  const int t = threadIdx.x;
  const int tx = t & 15, ty = t >> 4;
  float acc[4][4] = {};

  for (int k0 = 0; k0 < K; k0 += BK) {
    // A tile: 64x16 -> transposed into As[k][m]
#pragma unroll
    for (int j = 0; j < 4; ++j) {
      int idx = j * 256 + t;
      int r = idx >> 4, c = idx & 15;
      As[c][r] = Ab[(long)(m0 + r) * K + (k0 + c)];
    }
    if (!BT) {
      // B tile: 16x64, already K-major
#pragma unroll
      for (int j = 0; j < 4; ++j) {
        int idx = j * 256 + t;
        int r = idx >> 6, c = idx & 63;
        Bs[r][c] = Bp[(long)(k0 + r) * N + (n0 + c)];
      }
    } else {
      // B tile: 64 rows (n) x 16 cols (k) -> transpose into Bs[k][n]
#pragma unroll
      for (int j = 0; j < 4; ++j) {
        int idx = j * 256 + t;
        int n = idx >> 4, c = idx & 15;
        Bs[c][n] = Bp[(long)(n0 + n) * K + (k0 + c)];
      }
    }
    __syncthreads();
#pragma unroll
    for (int kk = 0; kk < BK; ++kk) {
      float4 av = *(const float4*)&As[kk][ty * 4];
      float4 bv = *(const float4*)&Bs[kk][tx * 4];
      float a[4] = {av.x, av.y, av.z, av.w};
      float b[4] = {bv.x, bv.y, bv.z, bv.w};
#pragma unroll
      for (int i = 0; i < 4; ++i)
#pragma unroll
        for (int j = 0; j < 4; ++j) acc[i][j] += a[i] * b[j];
    }
    __syncthreads();
  }

#pragma unroll
  for (int i = 0; i < 4; ++i) {
    int m = m0 + ty * 4 + i;
    float4 ov;
    float* o = (float*)&ov;
#pragma unroll
    for (int j = 0; j < 4; ++j) {
      float v = acc[i][j];
      if (BIAS == 1) v += bias[n0 + tx * 4 + j];
      if (BIAS == 2) v += bias[m];
      o[j] = v;
    }
    *(float4*)&Cb[(long)m * N + n0 + tx * 4] = ov;
  }
}

// ---------------------------------------------------------------------------
// z[i,r] = -(0.5/D) * sum_d (q[i,d]-centers[r,d])^2 * iw[r,d]
// (identical math to qq - 2qc + cc in the reference, fused in one pass)
// Same tiling as gemm_tile with three LDS tiles.
// ---------------------------------------------------------------------------
__global__ __launch_bounds__(256) void z_tile(const float* __restrict__ Q,
                                              const float* __restrict__ Cn,
                                              const float* __restrict__ Iw,
                                              float* __restrict__ Z) {
  constexpr int BM = 64, BN = 64, BK = 16, PAD = 4;
  __shared__ float Qs[BK][BM + PAD];
  __shared__ float Cs[BK][BN + PAD];
  __shared__ float Ws[BK][BN + PAD];
  const int n0 = blockIdx.x * BN;
  const int m0 = blockIdx.y * BM;
  const int t = threadIdx.x;
  const int tx = t & 15, ty = t >> 4;
  float acc[4][4] = {};

  for (int k0 = 0; k0 < Dd; k0 += BK) {
#pragma unroll
    for (int j = 0; j < 4; ++j) {
      int idx = j * 256 + t;
      int r = idx >> 4, c = idx & 15;
      Qs[c][r] = Q[(long)(m0 + r) * Dd + (k0 + c)];
      Cs[c][r] = Cn[(long)(n0 + r) * Dd + (k0 + c)];
      Ws[c][r] = Iw[(long)(n0 + r) * Dd + (k0 + c)];
    }
    __syncthreads();
#pragma unroll
    for (int kk = 0; kk < BK; ++kk) {
      float4 qv = *(const float4*)&Qs[kk][ty * 4];
      float4 cv = *(const float4*)&Cs[kk][tx * 4];
      float4 wv = *(const float4*)&Ws[kk][tx * 4];
      float q[4] = {qv.x, qv.y, qv.z, qv.w};
      float c[4] = {cv.x, cv.y, cv.z, cv.w};
      float w[4] = {wv.x, wv.y, wv.z, wv.w};
#pragma unroll
      for (int i = 0; i < 4; ++i)
#pragma unroll
        for (int j = 0; j < 4; ++j) {
          float d = q[i] - c[j];
          acc[i][j] += d * d * w[j];
        }
    }
    __syncthreads();
  }

  const float s = -0.5f / (float)Dd;
#pragma unroll
  for (int i = 0; i < 4; ++i) {
    int m = m0 + ty * 4 + i;
    float4 ov;
    float* o = (float*)&ov;
#pragma unroll
    for (int j = 0; j < 4; ++j) o[j] = acc[i][j] * s;
    *(float4*)&Z[(long)m * Rr + n0 + tx * 4] = ov;
  }
}

// ---------------------------------------------------------------------------
// In-place row softmax over R=512. One wave (64 lanes) per row, 8 floats/lane.
// ---------------------------------------------------------------------------
__global__ __launch_bounds__(256) void softmax_kernel(float* __restrict__ Z) {
  const int wave = threadIdx.x >> 6;
  const int lane = threadIdx.x & 63;
  const long row = (long)blockIdx.x * 4 + wave;
  float* p = Z + row * Rr;
  float4 v0 = *(float4*)&p[lane * 8];
  float4 v1 = *(float4*)&p[lane * 8 + 4];
  float v[8] = {v0.x, v0.y, v0.z, v0.w, v1.x, v1.y, v1.z, v1.w};
  float m = v[0];
#pragma unroll
  for (int i = 1; i < 8; ++i) m = fmaxf(m, v[i]);
#pragma unroll
  for (int s = 32; s > 0; s >>= 1) m = fmaxf(m, __shfl_xor(m, s, 64));
  float sum = 0.f;
#pragma unroll
  for (int i = 0; i < 8; ++i) {
    v[i] = __expf(v[i] - m);
    sum += v[i];
  }
#pragma unroll
  for (int s = 32; s > 0; s >>= 1) sum += __shfl_xor(sum, s, 64);
  float inv = 1.0f / sum;
#pragma unroll
  for (int i = 0; i < 8; ++i) v[i] *= inv;
  *(float4*)&p[lane * 8] = make_float4(v[0], v[1], v[2], v[3]);
  *(float4*)&p[lane * 8 + 4] = make_float4(v[4], v[5], v[6], v[7]);
}

// ---------------------------------------------------------------------------
extern "C" void kernel_launch(void* const* d_in, const int* in_sizes, int n_in,
                              void* d_out, int out_size, void* d_ws, size_t ws_size,
                              hipStream_t stream) {
  const float* query   = (const float*)d_in[0];  // (B, L, D)
  const float* Wq      = (const float*)d_in[1];  // (D, D)
  const float* bq      = (const float*)d_in[2];  // (D,)
  const float* Wc      = (const float*)d_in[3];  // (R, L)
  const float* bc      = (const float*)d_in[4];  // (R,)
  const float* centers = (const float*)d_in[5];  // (R, D)
  const float* widths  = (const float*)d_in[6];  // (R, D)
  float* out = (float*)d_out;                    // (B, L, D)

  float* ws = (float*)d_ws;
  float* q    = ws;                               // M1 * D   = 32 MB
  float* fss  = q + (long)M1 * Dd;                // M1 * R   = 32 MB (z, then softmax in-place)
  float* conq = fss + (long)M1 * Rr;              // B * R * D = 8 MB
  float* iw   = conq + (long)Bb * Rr * Dd;        // R * D    = 1 MB

  // 1) inv widths^2
  inv_w2_kernel<<<(Rr * Dd + 255) / 256, 256, 0, stream>>>(widths, iw, Rr * Dd);

  // 2) q = query @ Wq^T + bq       (M1 x D) = (M1 x D) x (D x D)^T
  gemm_tile<true, 1><<<dim3(Dd / 64, M1 / 64, 1), 256, 0, stream>>>(
      query, Wq, bq, q, M1, Dd, Dd, 0, 0, 0);

  // 3) z = -(0.5/D) * sum_d (q - c)^2 * iw    -> fss buffer
  z_tile<<<dim3(Rr / 64, M1 / 64, 1), 256, 0, stream>>>(q, centers, iw, fss);

  // 4) softmax over R, in place
  softmax_kernel<<<M1 / 4, 256, 0, stream>>>(fss);

  // 5) conq[b] = Wc @ query[b] + bc[r]   (R x D) = (R x L) x (L x D)
  gemm_tile<false, 2><<<dim3(Dd / 64, Rr / 64, Bb), 256, 0, stream>>>(
      Wc, query, bc, conq, Rr, Dd, Ls, 0, (long)Ls * Dd, (long)Rr * Dd);

  // 6) out[b] = Fss[b] @ conq[b]   (L x D) = (L x R) x (R x D)
  gemm_tile<false, 0><<<dim3(Dd / 64, Ls / 64, Bb), 256, 0, stream>>>(
      fss, conq, nullptr, out, Ls, Dd, Rr, (long)Ls * Rr, (long)Rr * Dd, (long)Ls * Dd);
}

// Round 2
// 335.283 us; speedup vs baseline: 2.2662x; 2.2662x over previous
//
#include <hip/hip_runtime.h>
#include <hip/hip_bf16.h>

constexpr int Bb = 8, Ls = 2048, Dd = 512, Rr = 512;
constexpr int M1 = Bb * Ls;  // 16384

typedef __attribute__((ext_vector_type(8))) short s8v;   // 8 bf16 (4 VGPRs)
typedef __attribute__((ext_vector_type(4))) float f4v;   // 4 fp32

// ---------------------------------------------------------------------------
// bf16 split helpers: x ~= hi + lo, |err| ~ 2^-17 |x|
// ---------------------------------------------------------------------------
__device__ __forceinline__ unsigned short bf16_rne(float x) {
  union { float f; unsigned u; } c{x};
  unsigned r = c.u + 0x7fff + ((c.u >> 16) & 1);
  return (unsigned short)(r >> 16);
}
__device__ __forceinline__ float bf16_f(unsigned short h) {
  union { unsigned u; float f; } c{(unsigned)h << 16};
  return c.f;
}
__device__ __forceinline__ void split2(float x, unsigned short& h, unsigned short& l) {
  h = bf16_rne(x);
  l = bf16_rne(x - bf16_f(h));
}

__device__ __forceinline__ void async_copy16(const void* g, void* l) {
  __builtin_amdgcn_global_load_lds((const __attribute__((address_space(1))) unsigned int*)g,
                                   (__attribute__((address_space(3))) unsigned int*)l, 16, 0, 0);
}

// ---------------------------------------------------------------------------
// split_query: read query (B,L,D) fp32; write split bf16 (qs_hi/lo, row-major)
// AND split bf16 transposed per batch (qt_hi/lo: (B,D,L)).
// Block (32,8), grid (D/32, L/32, B). 32x32 tile via LDS.
// ---------------------------------------------------------------------------
__global__ __launch_bounds__(256) void split_query(
    const float* __restrict__ q, unsigned short* __restrict__ qh,
    unsigned short* __restrict__ ql, unsigned short* __restrict__ qth,
    unsigned short* __restrict__ qtl) {
  __shared__ float t[32][33];
  const int b = blockIdx.z, l0 = blockIdx.y * 32, d0 = blockIdx.x * 32;
  const int tx = threadIdx.x, ty = threadIdx.y;
#pragma unroll
  for (int i = 0; i < 4; ++i) {
    int l = ty + i * 8;
    long off = ((long)b * Ls + l0 + l) * Dd + d0 + tx;
    float v = q[off];
    t[l][tx] = v;
    unsigned short h, lo;
    split2(v, h, lo);
    qh[off] = h;
    ql[off] = lo;
  }
  __syncthreads();
#pragma unroll
  for (int i = 0; i < 4; ++i) {
    int d = ty + i * 8;
    float v = t[tx][d];  // q[l0+tx][d0+d]
    unsigned short h, lo;
    split2(v, h, lo);
    long off = ((long)b * Dd + d0 + d) * Ls + l0 + tx;
    qth[off] = h;
    qtl[off] = lo;
  }
}

// ---------------------------------------------------------------------------
// split_mat: elementwise fp32 -> (hi, lo) bf16
// ---------------------------------------------------------------------------
__global__ __launch_bounds__(256) void split_mat(const float* __restrict__ a,
                                                 unsigned short* __restrict__ h,
                                                 unsigned short* __restrict__ l, int n) {
  int i = blockIdx.x * 256 + threadIdx.x;
  if (i < n) {
    unsigned short x, y;
    split2(a[i], x, y);
    h[i] = x;
    l[i] = y;
  }
}

// ---------------------------------------------------------------------------
// build_bz: Bz[r, 0:512] = 1/w^2 ; Bz[r, 512:1024] = -2*c/w^2 ; cc[r]=sum c^2/w^2
// One wave per row; grid R/4, block 256.
// ---------------------------------------------------------------------------
__global__ __launch_bounds__(256) void build_bz(const float* __restrict__ centers,
                                                const float* __restrict__ widths,
                                                unsigned short* __restrict__ bzh,
                                                unsigned short* __restrict__ bzl,
                                                float* __restrict__ cc) {
  const int wave = threadIdx.x >> 6, lane = threadIdx.x & 63;
  const int r = blockIdx.x * 4 + wave;
  float s = 0.f;
#pragma unroll
  for (int j = 0; j < 8; ++j) {
    int d = j * 64 + lane;
    float c = centers[(long)r * Dd + d];
    float w = widths[(long)r * Dd + d];
    float iw = 1.0f / (w * w);
    unsigned short h, l;
    split2(iw, h, l);
    bzh[(long)r * 1024 + d] = h;
    bzl[(long)r * 1024 + d] = l;
    float m2 = -2.0f * c * iw;
    split2(m2, h, l);
    bzh[(long)r * 1024 + 512 + d] = h;
    bzl[(long)r * 1024 + 512 + d] = l;
    s += c * c * iw;
  }
#pragma unroll
  for (int o = 32; o > 0; o >>= 1) s += __shfl_xor(s, o, 64);
  if (lane == 0) cc[r] = s;
}

// ---------------------------------------------------------------------------
// Split-bf16 MFMA GEMM: C = A * B^T (+epilogue). A: M x K, B: N x K, both
// row-major K-major, each as (hi, lo) bf16 pair. 128x128 tile, BK=32,
// 256 threads = 4 waves (2x2), each wave 64x64 = 4x4 mfma 16x16x32 tiles,
// 3 MFMAs per tile-pair (hi*hi + hi*lo + lo*hi).
// EPI: 0 = q-GEMM  (v=acc+bias[n]; write split(v*v) at col n, split(v) at col
//                   512+n of Chi/Clo with row stride ldC=1024)
//      1 = z-GEMM  (Cf = (acc+bias[n]) * (-1/1024))
//      2 = conqT   (write split(acc+bias[n]) to Chi/Clo)
//      3 = out     (Cf = acc)
// ---------------------------------------------------------------------------
template <int EPI>
__global__ __launch_bounds__(256) void mfma_gemm(
    const unsigned short* __restrict__ Ahi, const unsigned short* __restrict__ Alo,
    const unsigned short* __restrict__ Bhi, const unsigned short* __restrict__ Blo,
    const float* __restrict__ bias, float* __restrict__ Cf,
    unsigned short* __restrict__ Chi, unsigned short* __restrict__ Clo,
    int M, int N, int K, int ldC, long sA, long sB, long sC) {
  __shared__ unsigned short Ah[128 * 32], Al[128 * 32], Bh[128 * 32], Bl[128 * 32];
  const int n0 = blockIdx.x * 128;
  const int m0 = blockIdx.y * 128;
  const long bz = blockIdx.z;
  const unsigned short* Ahb = Ahi + bz * sA;
  const unsigned short* Alb = Alo + bz * sA;
  const unsigned short* Bhb = Bhi + bz * sB;
  const unsigned short* Blb = Blo + bz * sB;

  const int tid = threadIdx.x;
  const int wave = tid >> 6, lane = tid & 63;
  const int wm = wave >> 1, wn = wave & 1;
  const int quad = lane >> 4, tr = lane & 15;

  f4v acc[4][4] = {};

  const int lrow = lane >> 2;          // 0..15 within a 16-row staging chunk
  const int lcol = (lane & 3) * 8;     // element offset of this lane's 16B

  for (int k0 = 0; k0 < K; k0 += 32) {
    __syncthreads();  // previous compute done before LDS overwrite
    {
      const int r0 = wave * 32;
#pragma unroll
      for (int h = 0; h < 2; ++h) {
        const int rr = r0 + h * 16;
        const long arow = (long)(m0 + rr + lrow) * K + k0 + lcol;
        const long brow = (long)(n0 + rr + lrow) * K + k0 + lcol;
        async_copy16(Ahb + arow, Ah + rr * 32);
        async_copy16(Alb + arow, Al + rr * 32);
        async_copy16(Bhb + brow, Bh + rr * 32);
        async_copy16(Blb + brow, Bl + rr * 32);
      }
    }
    __syncthreads();  // drains vmcnt(0): LDS tiles ready

    s8v afh[4], afl[4], bfh[4], bfl[4];
#pragma unroll
    for (int i = 0; i < 4; ++i) {
      const int am = (wm * 64 + i * 16 + tr) * 32 + quad * 8;
      afh[i] = *(const s8v*)&Ah[am];
      afl[i] = *(const s8v*)&Al[am];
      const int bn = (wn * 64 + i * 16 + tr) * 32 + quad * 8;
      bfh[i] = *(const s8v*)&Bh[bn];
      bfl[i] = *(const s8v*)&Bl[bn];
    }
#pragma unroll
    for (int i = 0; i < 4; ++i)
#pragma unroll
      for (int j = 0; j < 4; ++j) {
        acc[i][j] = __builtin_amdgcn_mfma_f32_16x16x32_bf16(afl[i], bfh[j], acc[i][j], 0, 0, 0);
        acc[i][j] = __builtin_amdgcn_mfma_f32_16x16x32_bf16(afh[i], bfl[j], acc[i][j], 0, 0, 0);
        acc[i][j] = __builtin_amdgcn_mfma_f32_16x16x32_bf16(afh[i], bfh[j], acc[i][j], 0, 0, 0);
      }
  }

  // Epilogue. D[row = quad*4 + reg][col = tr] per 16x16 tile (m89-verified).
  float* Cfb = Cf ? Cf + bz * sC : nullptr;
  unsigned short* Chb = Chi ? Chi + bz * sC : nullptr;
  unsigned short* Clb = Clo ? Clo + bz * sC : nullptr;
  const float zscale = -0.0009765625f;  // -(0.5/512)
#pragma unroll
  for (int i = 0; i < 4; ++i)
#pragma unroll
    for (int j = 0; j < 4; ++j) {
      const int rbase = m0 + wm * 64 + i * 16 + quad * 4;
      const int cg = n0 + wn * 64 + j * 16 + tr;
#pragma unroll
      for (int r = 0; r < 4; ++r) {
        const float v = acc[i][j][r];
        const long row = rbase + r;
        if (EPI == 0) {
          const float qv = v + bias[cg];
          unsigned short h, l;
          split2(qv * qv, h, l);
          Chb[row * (long)ldC + cg] = h;
          Clb[row * (long)ldC + cg] = l;
          split2(qv, h, l);
          Chb[row * (long)ldC + 512 + cg] = h;
          Clb[row * (long)ldC + 512 + cg] = l;
        } else if (EPI == 1) {
          Cfb[row * (long)ldC + cg] = (v + bias[cg]) * zscale;
        } else if (EPI == 2) {
          unsigned short h, l;
          split2(v + bias[cg], h, l);
          Chb[row * (long)ldC + cg] = h;
          Clb[row * (long)ldC + cg] = l;
        } else {
          Cfb[row * (long)ldC + cg] = v;
        }
      }
    }
}

// ---------------------------------------------------------------------------
// softmax over R=512, reading z fp32, writing split bf16 Fss. One wave/row.
// ---------------------------------------------------------------------------
__global__ __launch_bounds__(256) void softmax_split(const float* __restrict__ Z,
                                                     unsigned short* __restrict__ fh,
                                                     unsigned short* __restrict__ fl) {
  const int wave = threadIdx.x >> 6;
  const int lane = threadIdx.x & 63;
  const long row = (long)blockIdx.x * 4 + wave;
  const float* p = Z + row * Rr;
  float4 v0 = *(const float4*)&p[lane * 8];
  float4 v1 = *(const float4*)&p[lane * 8 + 4];
  float v[8] = {v0.x, v0.y, v0.z, v0.w, v1.x, v1.y, v1.z, v1.w};
  float m = v[0];
#pragma unroll
  for (int i = 1; i < 8; ++i) m = fmaxf(m, v[i]);
#pragma unroll
  for (int s = 32; s > 0; s >>= 1) m = fmaxf(m, __shfl_xor(m, s, 64));
  float sum = 0.f;
#pragma unroll
  for (int i = 0; i < 8; ++i) {
    v[i] = __expf(v[i] - m);
    sum += v[i];
  }
#pragma unroll
  for (int s = 32; s > 0; s >>= 1) sum += __shfl_xor(sum, s, 64);
  const float inv = 1.0f / sum;
  s8v hv, lv;
#pragma unroll
  for (int i = 0; i < 8; ++i) {
    unsigned short h, l;
    split2(v[i] * inv, h, l);
    hv[i] = (short)h;
    lv[i] = (short)l;
  }
  *(s8v*)&fh[row * Rr + lane * 8] = hv;
  *(s8v*)&fl[row * Rr + lane * 8] = lv;
}

// ---------------------------------------------------------------------------
extern "C" void kernel_launch(void* const* d_in, const int* in_sizes, int n_in,
                              void* d_out, int out_size, void* d_ws, size_t ws_size,
                              hipStream_t stream) {
  const float* query   = (const float*)d_in[0];
  const float* Wq      = (const float*)d_in[1];
  const float* bq      = (const float*)d_in[2];
  const float* Wc      = (const float*)d_in[3];
  const float* bc      = (const float*)d_in[4];
  const float* centers = (const float*)d_in[5];
  const float* widths  = (const float*)d_in[6];
  float* out = (float*)d_out;

  // Workspace layout (~150 MB), regions reused across the pipeline:
  char* base = (char*)d_ws;
  auto alloc = [&](size_t bytes) {
    char* p = base;
    base += (bytes + 255) & ~(size_t)255;
    return p;
  };
  const size_t half = (size_t)M1 * Dd * 2;  // 16.78 MB (one bf16 M1 x 512 mat)
  // R1: qs_hi/lo  -> later z (fp32)
  char* R1 = alloc(2 * half);
  unsigned short* qs_hi = (unsigned short*)R1;
  unsigned short* qs_lo = (unsigned short*)(R1 + half);
  float* z = (float*)R1;
  // R2: qt_hi/lo (B, D, L)
  char* R2 = alloc(2 * half);
  unsigned short* qt_hi = (unsigned short*)R2;
  unsigned short* qt_lo = (unsigned short*)(R2 + half);
  // R3: Az_hi/lo (M1 x 1024) -> later Fss hi/lo
  char* R3 = alloc(4 * half);
  unsigned short* az_hi = (unsigned short*)R3;
  unsigned short* az_lo = (unsigned short*)(R3 + 2 * half);
  unsigned short* fs_hi = (unsigned short*)R3;
  unsigned short* fs_lo = (unsigned short*)(R3 + half);
  // R4: weights & small mats
  unsigned short* wq_hi = (unsigned short*)alloc((size_t)Dd * Dd * 2);
  unsigned short* wq_lo = (unsigned short*)alloc((size_t)Dd * Dd * 2);
  unsigned short* wc_hi = (unsigned short*)alloc((size_t)Rr * Ls * 2);
  unsigned short* wc_lo = (unsigned short*)alloc((size_t)Rr * Ls * 2);
  unsigned short* bz_hi = (unsigned short*)alloc((size_t)Rr * 1024 * 2);
  unsigned short* bz_lo = (unsigned short*)alloc((size_t)Rr * 1024 * 2);
  float* cc = (float*)alloc((size_t)Rr * 4);
  unsigned short* cq_hi = (unsigned short*)alloc((size_t)Bb * Dd * Rr * 2);
  unsigned short* cq_lo = (unsigned short*)alloc((size_t)Bb * Dd * Rr * 2);

  // 1) split + transpose query
  split_query<<<dim3(Dd / 32, Ls / 32, Bb), dim3(32, 8), 0, stream>>>(
      query, qs_hi, qs_lo, qt_hi, qt_lo);
  // 2) split weights
  split_mat<<<(Dd * Dd + 255) / 256, 256, 0, stream>>>(Wq, wq_hi, wq_lo, Dd * Dd);
  split_mat<<<(Rr * Ls + 255) / 256, 256, 0, stream>>>(Wc, wc_hi, wc_lo, Rr * Ls);
  // 3) Bz + cc from centers/widths
  build_bz<<<Rr / 4, 256, 0, stream>>>(centers, widths, bz_hi, bz_lo, cc);

  // 4) q-GEMM: q = query @ Wq^T + bq; epilogue writes Az = [q^2, q] split
  mfma_gemm<0><<<dim3(Dd / 128, M1 / 128, 1), 256, 0, stream>>>(
      qs_hi, qs_lo, wq_hi, wq_lo, bq, nullptr, az_hi, az_lo,
      M1, Dd, Dd, 1024, 0, 0, 0);

  // 5) z-GEMM: z = -(Az @ Bz^T + cc) / 1024   (K = 1024)
  mfma_gemm<1><<<dim3(Rr / 128, M1 / 128, 1), 256, 0, stream>>>(
      az_hi, az_lo, bz_hi, bz_lo, cc, z, nullptr, nullptr,
      M1, Rr, 1024, Rr, 0, 0, 0);

  // 6) softmax -> Fss split (overwrites Az region)
  softmax_split<<<M1 / 4, 256, 0, stream>>>(z, fs_hi, fs_lo);

  // 7) conqT-GEMM: conqT[b] (D x R) = qT[b] @ Wc^T + bc   (K = L = 2048)
  mfma_gemm<2><<<dim3(Rr / 128, Dd / 128, Bb), 256, 0, stream>>>(
      qt_hi, qt_lo, wc_hi, wc_lo, bc, nullptr, cq_hi, cq_lo,
      Dd, Rr, Ls, Rr, (long)Dd * Ls, 0, (long)Dd * Rr);

  // 8) out-GEMM: out[b] = Fss[b] @ conqT[b]^T   (K = R = 512)
  mfma_gemm<3><<<dim3(Dd / 128, Ls / 128, Bb), 256, 0, stream>>>(
      fs_hi, fs_lo, cq_hi, cq_lo, nullptr, out, nullptr, nullptr,
      Ls, Dd, Rr, Dd, (long)Ls * Rr, (long)Dd * Rr, (long)Ls * Dd);
}

// Round 3
// 212.329 us; speedup vs baseline: 3.5786x; 1.5791x over previous
//
#include <hip/hip_runtime.h>
#include <hip/hip_bf16.h>

constexpr int Bb = 8, Ls = 2048, Dd = 512, Rr = 512;
constexpr int M1 = Bb * Ls;  // 16384

typedef _Float16 h8v __attribute__((ext_vector_type(8)));  // 8 fp16 (4 VGPRs)
typedef _Float16 h4v __attribute__((ext_vector_type(4)));  // 4 fp16 (8 B)
typedef float f4v __attribute__((ext_vector_type(4)));     // 4 fp32

__device__ __forceinline__ void async_copy16(const void* g, void* l) {
  __builtin_amdgcn_global_load_lds((const __attribute__((address_space(1))) unsigned int*)g,
                                   (__attribute__((address_space(3))) unsigned int*)l, 16, 0, 0);
}

// ---------------------------------------------------------------------------
// cvt_query: query (B,L,D) fp32 -> qs fp16 (B,L,D) and qt fp16 (B,D,L).
// 64x64 tiles, 256 threads, float4 loads, 8B fp16 stores both sides.
// ---------------------------------------------------------------------------
__global__ __launch_bounds__(256) void cvt_query(const float* __restrict__ q,
                                                 _Float16* __restrict__ qs,
                                                 _Float16* __restrict__ qt) {
  __shared__ float t[64][65];
  const int b = blockIdx.z, l0 = blockIdx.y * 64, d0 = blockIdx.x * 64;
  const int tid = threadIdx.x;
  const int r = tid >> 4, c4 = (tid & 15) * 4;
#pragma unroll
  for (int i = 0; i < 4; ++i) {
    const int l = r + i * 16;
    const float4 v = *(const float4*)&q[((long)b * Ls + l0 + l) * Dd + d0 + c4];
    t[l][c4] = v.x; t[l][c4 + 1] = v.y; t[l][c4 + 2] = v.z; t[l][c4 + 3] = v.w;
    h4v h = {(_Float16)v.x, (_Float16)v.y, (_Float16)v.z, (_Float16)v.w};
    *(h4v*)&qs[((long)b * Ls + l0 + l) * Dd + d0 + c4] = h;
  }
  __syncthreads();
#pragma unroll
  for (int i = 0; i < 4; ++i) {
    const int d = r + i * 16;
    h4v h = {(_Float16)t[c4][d], (_Float16)t[c4 + 1][d],
             (_Float16)t[c4 + 2][d], (_Float16)t[c4 + 3][d]};
    *(h4v*)&qt[((long)b * Dd + d0 + d) * Ls + l0 + c4] = h;
  }
}

// ---------------------------------------------------------------------------
// cvt_mat: fp32 -> fp16 elementwise, 4 per thread
// ---------------------------------------------------------------------------
__global__ __launch_bounds__(256) void cvt_mat(const float* __restrict__ a,
                                               _Float16* __restrict__ h, int n4) {
  int i = blockIdx.x * 256 + threadIdx.x;
  if (i < n4) {
    float4 v = *(const float4*)&a[i * 4];
    h4v o = {(_Float16)v.x, (_Float16)v.y, (_Float16)v.z, (_Float16)v.w};
    *(h4v*)&h[i * 4] = o;
  }
}

// ---------------------------------------------------------------------------
// build_bz: Bz[r,0:512]=1/w^2 ; Bz[r,512:1024]=-2*c/w^2 (fp16); cc[r]=sum c^2/w^2
// ---------------------------------------------------------------------------
__global__ __launch_bounds__(256) void build_bz(const float* __restrict__ centers,
                                                const float* __restrict__ widths,
                                                _Float16* __restrict__ bz,
                                                float* __restrict__ cc) {
  const int wave = threadIdx.x >> 6, lane = threadIdx.x & 63;
  const int r = blockIdx.x * 4 + wave;
  float s = 0.f;
#pragma unroll
  for (int j = 0; j < 8; ++j) {
    int d = j * 64 + lane;
    float c = centers[(long)r * Dd + d];
    float w = widths[(long)r * Dd + d];
    float iw = 1.0f / (w * w);
    bz[(long)r * 1024 + d] = (_Float16)iw;
    bz[(long)r * 1024 + 512 + d] = (_Float16)(-2.0f * c * iw);
    s += c * c * iw;
  }
#pragma unroll
  for (int o = 32; o > 0; o >>= 1) s += __shfl_xor(s, o, 64);
  if (lane == 0) cc[r] = s;
}

// ---------------------------------------------------------------------------
// fp16 MFMA GEMM: C = A * B^T (+epilogue). A: M x K, B: N x K, both K-major
// fp16. Block tile (AI*32) x 128, BK=32, 256 threads = 4 waves (2x2); each
// wave (AI*16) x 64 = AI x 4 mfma_f32_16x16x32_f16 tiles. m97 structure:
// global_load_lds width 16 staging, 16 KB LDS total for AI=4.
// EPI: 0 = q-GEMM (qv=acc+bias[n]; Az row: col n <- qv^2, col 512+n <- qv)
//      1 = z-GEMM (Cf = (acc+bias[n]) * (-1/1024))
//      2 = conqT  (Ch = fp16(acc+bias[n]))
//      3 = out    (Cf = acc)
// ---------------------------------------------------------------------------
template <int AI, int EPI>
__global__ __launch_bounds__(256) void gemm_h(
    const _Float16* __restrict__ A, const _Float16* __restrict__ Bm,
    const float* __restrict__ bias, float* __restrict__ Cf,
    _Float16* __restrict__ Ch, int K, int ldC, long sA, long sB, long sC) {
  constexpr int TM = AI * 32;
  __shared__ _Float16 As[TM * 32];
  __shared__ _Float16 Bs[128 * 32];
  const int n0 = blockIdx.x * 128;
  const int m0 = blockIdx.y * TM;
  const long bz = blockIdx.z;
  const _Float16* Ab = A + bz * sA;
  const _Float16* Bb = Bm + bz * sB;

  const int tid = threadIdx.x;
  const int wave = tid >> 6, lane = tid & 63;
  const int wm = wave >> 1, wn = wave & 1;
  const int quad = lane >> 4, tr = lane & 15;
  const int lrow = lane >> 2;        // 0..15 row within a 16-row chunk
  const int lcol = (lane & 3) * 8;   // fp16 element offset of this lane's 16B

  f4v acc[AI][4];
#pragma unroll
  for (int i = 0; i < AI; ++i)
#pragma unroll
    for (int j = 0; j < 4; ++j) acc[i][j] = (f4v){0.f, 0.f, 0.f, 0.f};

  for (int k0 = 0; k0 < K; k0 += 32) {
    __syncthreads();  // previous compute done before LDS overwrite
#pragma unroll
    for (int c = wave; c < TM / 16; c += 4) {
      const long g = (long)(m0 + c * 16 + lrow) * K + k0 + lcol;
      async_copy16(Ab + g, As + c * 512);
    }
#pragma unroll
    for (int c = wave; c < 8; c += 4) {
      const long g = (long)(n0 + c * 16 + lrow) * K + k0 + lcol;
      async_copy16(Bb + g, Bs + c * 512);
    }
    __syncthreads();  // drains vmcnt(0): tiles ready

    h8v af[AI], bf[4];
#pragma unroll
    for (int i = 0; i < AI; ++i)
      af[i] = *(const h8v*)&As[(wm * (AI * 16) + i * 16 + tr) * 32 + quad * 8];
#pragma unroll
    for (int j = 0; j < 4; ++j)
      bf[j] = *(const h8v*)&Bs[(wn * 64 + j * 16 + tr) * 32 + quad * 8];
#pragma unroll
    for (int i = 0; i < AI; ++i)
#pragma unroll
      for (int j = 0; j < 4; ++j)
        acc[i][j] = __builtin_amdgcn_mfma_f32_16x16x32_f16(af[i], bf[j], acc[i][j], 0, 0, 0);
  }

  // Epilogue. C/D layout per 16x16 tile: col = tr, row = quad*4 + reg.
  float* Cfb = Cf ? Cf + bz * sC : nullptr;
  _Float16* Chb = Ch ? Ch + bz * sC : nullptr;
  const float zscale = -0.0009765625f;  // -(0.5/512)
#pragma unroll
  for (int i = 0; i < AI; ++i)
#pragma unroll
    for (int j = 0; j < 4; ++j) {
      const int rbase = m0 + wm * (AI * 16) + i * 16 + quad * 4;
      const int cg = n0 + wn * 64 + j * 16 + tr;
#pragma unroll
      for (int r = 0; r < 4; ++r) {
        const float v = acc[i][j][r];
        const long row = rbase + r;
        if (EPI == 0) {
          const float qv = v + bias[cg];
          Chb[row * (long)ldC + cg] = (_Float16)(qv * qv);
          Chb[row * (long)ldC + 512 + cg] = (_Float16)qv;
        } else if (EPI == 1) {
          Cfb[row * (long)ldC + cg] = (v + bias[cg]) * zscale;
        } else if (EPI == 2) {
          Chb[row * (long)ldC + cg] = (_Float16)(v + bias[cg]);
        } else {
          Cfb[row * (long)ldC + cg] = v;
        }
      }
    }
}

// ---------------------------------------------------------------------------
// softmax over R=512: read z fp32, write Fss fp16. One wave per row.
// ---------------------------------------------------------------------------
__global__ __launch_bounds__(256) void softmax_h(const float* __restrict__ Z,
                                                 _Float16* __restrict__ F) {
  const int wave = threadIdx.x >> 6;
  const int lane = threadIdx.x & 63;
  const long row = (long)blockIdx.x * 4 + wave;
  const float* p = Z + row * Rr;
  float4 v0 = *(const float4*)&p[lane * 8];
  float4 v1 = *(const float4*)&p[lane * 8 + 4];
  float v[8] = {v0.x, v0.y, v0.z, v0.w, v1.x, v1.y, v1.z, v1.w};
  float m = v[0];
#pragma unroll
  for (int i = 1; i < 8; ++i) m = fmaxf(m, v[i]);
#pragma unroll
  for (int s = 32; s > 0; s >>= 1) m = fmaxf(m, __shfl_xor(m, s, 64));
  float sum = 0.f;
#pragma unroll
  for (int i = 0; i < 8; ++i) {
    v[i] = __expf(v[i] - m);
    sum += v[i];
  }
#pragma unroll
  for (int s = 32; s > 0; s >>= 1) sum += __shfl_xor(sum, s, 64);
  const float inv = 1.0f / sum;
  h8v o;
#pragma unroll
  for (int i = 0; i < 8; ++i) o[i] = (_Float16)(v[i] * inv);
  *(h8v*)&F[row * Rr + lane * 8] = o;
}

// ---------------------------------------------------------------------------
extern "C" void kernel_launch(void* const* d_in, const int* in_sizes, int n_in,
                              void* d_out, int out_size, void* d_ws, size_t ws_size,
                              hipStream_t stream) {
  const float* query   = (const float*)d_in[0];
  const float* Wq      = (const float*)d_in[1];
  const float* bq      = (const float*)d_in[2];
  const float* Wc      = (const float*)d_in[3];
  const float* bc      = (const float*)d_in[4];
  const float* centers = (const float*)d_in[5];
  const float* widths  = (const float*)d_in[6];
  float* out = (float*)d_out;

  char* base = (char*)d_ws;
  auto alloc = [&](size_t bytes) {
    char* p = base;
    base += (bytes + 255) & ~(size_t)255;
    return p;
  };
  _Float16* qs = (_Float16*)alloc((size_t)M1 * Dd * 2);        // 16.8 MB
  _Float16* qt = (_Float16*)alloc((size_t)M1 * Dd * 2);        // 16.8 MB (B,D,L)
  _Float16* az = (_Float16*)alloc((size_t)M1 * 1024 * 2);      // 33.6 MB
  float*    z  = (float*)alloc((size_t)M1 * Rr * 4);           // 33.6 MB
  _Float16* fs = (_Float16*)alloc((size_t)M1 * Rr * 2);        // 16.8 MB
  _Float16* wq = (_Float16*)alloc((size_t)Dd * Dd * 2);
  _Float16* wc = (_Float16*)alloc((size_t)Rr * Ls * 2);
  _Float16* bzm = (_Float16*)alloc((size_t)Rr * 1024 * 2);
  float*    cc = (float*)alloc((size_t)Rr * 4);
  _Float16* cq = (_Float16*)alloc((size_t)Bb * Dd * Rr * 2);   // 4.2 MB (B*D, R)

  // 1) conversions / small precompute
  cvt_query<<<dim3(Dd / 64, Ls / 64, Bb), 256, 0, stream>>>(query, qs, qt);
  cvt_mat<<<(Dd * Dd / 4 + 255) / 256, 256, 0, stream>>>(Wq, wq, Dd * Dd / 4);
  cvt_mat<<<(Rr * Ls / 4 + 255) / 256, 256, 0, stream>>>(Wc, wc, Rr * Ls / 4);
  build_bz<<<Rr / 4, 256, 0, stream>>>(centers, widths, bzm, cc);

  // 2) q-GEMM: q = query @ Wq^T + bq; epilogue writes Az = [q^2, q] fp16
  gemm_h<4, 0><<<dim3(Dd / 128, M1 / 128, 1), 256, 0, stream>>>(
      qs, wq, bq, nullptr, az, Dd, 1024, 0, 0, 0);

  // 3) z-GEMM: z = -(Az @ Bz^T + cc) / 1024   (K = 1024)
  gemm_h<4, 1><<<dim3(Rr / 128, M1 / 128, 1), 256, 0, stream>>>(
      az, bzm, cc, z, nullptr, 1024, Rr, 0, 0, 0);

  // 4) softmax -> Fss fp16
  softmax_h<<<M1 / 4, 256, 0, stream>>>(z, fs);

  // 5) conqT-GEMM as single M=B*D=4096 GEMM: cq[(b,d), r] = qt[(b,d),:] . Wc[r,:] + bc[r]
  //    64-row tiles -> grid (4, 64) = 256 blocks (1 per CU)
  gemm_h<2, 2><<<dim3(Rr / 128, (Bb * Dd) / 64, 1), 256, 0, stream>>>(
      qt, wc, bc, nullptr, cq, Ls, Rr, 0, 0, 0);

  // 6) out-GEMM: out[b] = Fss[b] @ cq[b]^T   (K = R = 512)
  gemm_h<4, 3><<<dim3(Dd / 128, Ls / 128, Bb), 256, 0, stream>>>(
      fs, cq, nullptr, out, nullptr, Rr, Dd,
      (long)Ls * Rr, (long)Dd * Rr, (long)Ls * Dd);
}